// Round 1
// baseline (298.944 us; speedup 1.0000x reference)
//
#include <hip/hip_runtime.h>

#define N_NODES 50000
#define N_EDGES 800000
#define D_FEAT 32
#define NUM_GRAPHS 64
#define FEATS 320
#define NBIN 128                         // bins of 512 nodes (98 used)
#define BINSH 9
#define CE 4096                          // edges per binning chunk
#define NCHUNK ((N_EDGES + CE - 1) / CE) // 196
#define NPB ((N_NODES + 511) / 512)      // 98 place blocks

// bf16 helpers (RNE pack, shift unpack) — edge weights stay bf16
__device__ __forceinline__ unsigned short f2bf(float f) {
    unsigned int u = __float_as_uint(f);
    u = (u + 0x7fffu + ((u >> 16) & 1u)) >> 16;
    return (unsigned short)u;
}
__device__ __forceinline__ float bf2f(unsigned short h) {
    return __uint_as_float((unsigned int)h << 16);
}

// biased-uint8 pack: q in [0,254], 4 per dword
__device__ __forceinline__ unsigned int pack8(int q0, int q1, int q2, int q3) {
    return (unsigned int)(q0 & 0xff) | ((unsigned int)(q1 & 0xff) << 8) |
           ((unsigned int)(q2 & 0xff) << 16) | ((unsigned int)(q3 & 0xff) << 24);
}

// ---------------- atomic-free binning sort (counts -> positions -> place) ----

__global__ void binA_kernel(const int* __restrict__ dst, int* __restrict__ counts, int n) {
    __shared__ int h[NBIN];
    int t = threadIdx.x;
    if (t < NBIN) h[t] = 0;
    __syncthreads();
    int s0 = blockIdx.x * CE, e0 = min(s0 + CE, n);
    for (int i = s0 + t; i < e0; i += blockDim.x)
        atomicAdd(&h[dst[i] >> BINSH], 1);
    __syncthreads();
    if (t < NBIN) counts[blockIdx.x * NBIN + t] = h[t];
}

__global__ void binB_kernel(int* __restrict__ counts, int* __restrict__ binBase) {
    __shared__ int s[NBIN];
    int b = threadIdx.x;
    int tot = 0;
    #pragma unroll 8
    for (int c = 0; c < NCHUNK; ++c) tot += counts[c * NBIN + b];
    s[b] = tot;
    __syncthreads();
    for (int off = 1; off < NBIN; off <<= 1) {
        int u = (b >= off) ? s[b - off] : 0;
        __syncthreads();
        s[b] += u;
        __syncthreads();
    }
    int base = s[b] - tot;   // exclusive
    binBase[b] = base;
    if (b == NBIN - 1) binBase[NBIN] = s[b];
    int running = base;
    #pragma unroll 4
    for (int c = 0; c < NCHUNK; ++c) {
        int idx = c * NBIN + b;
        int v = counts[idx];
        counts[idx] = running;
        running += v;
    }
}

__global__ __launch_bounds__(256) void binC_kernel(const int* __restrict__ src,
                                                   const int* __restrict__ dst,
                                                   const float* __restrict__ w,
                                                   const int* __restrict__ counts,
                                                   int2* __restrict__ tmp, int n) {
    __shared__ int h[NBIN], sc[NBIN], cur[NBIN], gbase[NBIN];
    __shared__ int2 srec[CE];
    __shared__ unsigned char sbin[CE];
    int t = threadIdx.x;
    if (t < NBIN) h[t] = 0;
    __syncthreads();
    int s0 = blockIdx.x * CE, e0 = min(s0 + CE, n);
    int cnt = e0 - s0;
    for (int i = s0 + t; i < e0; i += blockDim.x)
        atomicAdd(&h[dst[i] >> BINSH], 1);
    __syncthreads();
    if (t < NBIN) sc[t] = h[t];
    __syncthreads();
    for (int off = 1; off < NBIN; off <<= 1) {
        int u = (t < NBIN && t >= off) ? sc[t - off] : 0;
        __syncthreads();
        if (t < NBIN) sc[t] += u;   // inclusive; exclusive = sc[b]-h[b]
        __syncthreads();
    }
    if (t < NBIN) {
        cur[t] = 0;
        gbase[t] = counts[blockIdx.x * NBIN + t];
    }
    __syncthreads();
    for (int i = s0 + t; i < e0; i += blockDim.x) {
        int d = dst[i];
        int b = d >> BINSH;
        int pos = (sc[b] - h[b]) + atomicAdd(&cur[b], 1);   // LDS atomic: cheap
        srec[pos] = make_int2(src[i] | ((int)f2bf(w[i]) << 16), d & 511);
        sbin[pos] = (unsigned char)b;
    }
    __syncthreads();
    for (int j = t; j < cnt; j += blockDim.x) {
        int b = sbin[j];
        tmp[gbase[b] + (j - (sc[b] - h[b]))] = srec[j];   // coalesced runs per bin
    }
}

__global__ __launch_bounds__(256) void place_kernel(const int* __restrict__ binBase,
                                                    const int2* __restrict__ tmp,
                                                    unsigned int* __restrict__ edges,
                                                    int* __restrict__ rowptr, int n) {
    __shared__ int h[512], sc[512], cur[512];
    int b = blockIdx.x;
    int t = threadIdx.x;
    int base = binBase[b], end = binBase[b + 1];
    for (int i = t; i < 512; i += 256) { h[i] = 0; cur[i] = 0; }
    __syncthreads();
    for (int e = base + t; e < end; e += 256)
        atomicAdd(&h[tmp[e].y], 1);
    __syncthreads();
    for (int i = t; i < 512; i += 256) sc[i] = h[i];
    __syncthreads();
    for (int off = 1; off < 512; off <<= 1) {
        int i0 = t, i1 = t + 256;
        int a0 = (i0 >= off) ? sc[i0 - off] : 0;
        int a1 = (i1 >= off) ? sc[i1 - off] : 0;
        __syncthreads();
        sc[i0] += a0;
        sc[i1] += a1;
        __syncthreads();
    }
    int node0 = b << BINSH;
    for (int i = t; i < 512; i += 256) {
        int node = node0 + i;
        if (node <= n) rowptr[node] = base + sc[i] - h[i];   // exclusive
    }
    if (b == 0 && t == 0) rowptr[0] = 0;
    __syncthreads();
    for (int e = base + t; e < end; e += 256) {
        int2 p = tmp[e];
        int loc = p.y;
        int pos = base + (sc[loc] - h[loc]) + atomicAdd(&cur[loc], 1);
        edges[pos] = (unsigned int)p.x;
    }
}

// ---------------- prep: X -> per-node-scaled int8 + graph boundaries --------
// Per-node amax shared-exponent int8 (biased +127): ~7 effective mantissa bits
// at HALF the gather footprint of bf16. Chain state: 32B/node + fp32 scale.

__global__ void prep_kernel(const float4* __restrict__ xin, unsigned int* __restrict__ xout,
                            float* __restrict__ xsc,
                            const int* __restrict__ batch, int* __restrict__ gstart, int n) {
    int i = blockIdx.x * blockDim.x + threadIdx.x;
    if (i < n * 8) {
        float4 v = xin[i];
        float m = fmaxf(fmaxf(fabsf(v.x), fabsf(v.y)), fmaxf(fabsf(v.z), fabsf(v.w)));
        m = fmaxf(m, __shfl_xor(m, 1, 8));
        m = fmaxf(m, __shfl_xor(m, 2, 8));
        m = fmaxf(m, __shfl_xor(m, 4, 8));
        float inv = (m > 1e-30f) ? 127.f / m : 0.f;
        int q0 = __float2int_rn(v.x * inv) + 127;
        int q1 = __float2int_rn(v.y * inv) + 127;
        int q2 = __float2int_rn(v.z * inv) + 127;
        int q3 = __float2int_rn(v.w * inv) + 127;
        xout[i] = pack8(q0, q1, q2, q3);
        if ((i & 7) == 0) xsc[i >> 3] = (m > 1e-30f) ? m * (1.f / 127.f) : 0.f;
    }
    if (i < n) {
        int g = batch[i];
        int gp = (i == 0) ? -1 : batch[i - 1];
        for (int gg = gp + 1; gg <= g; ++gg) gstart[gg] = i;
        if (i == n - 1)
            for (int gg = g + 1; gg <= NUM_GRAPHS; ++gg) gstart[gg] = n;
    }
}

// ---------------- SpMM (pull, no atomics), D=32 int8+scale, 4B edge recs ----
// 8 lanes/node; lane owns cols 4l..4l+3 (one dword of biased uint8). fp32 accum.
// Structural limit (r8-r11): per-XCD L2 line-fill ~1/cy. bf16 state = 3.2MB =
// 50k lines/XCD => ~20us/step. int8+scale = 1.6MB+0.2MB = ~28k lines/XCD =>
// ~12us/step. Dequant via v_cvt_f32_ubyte pattern; bias folded out with
// acc -= 127*sum(w*scale), so per-edge VALU ~unchanged.

__global__ __launch_bounds__(256) void spmm_kernel(const unsigned int* __restrict__ xin,
                                                   const float* __restrict__ xsc,
                                                   unsigned int* __restrict__ yout,
                                                   float* __restrict__ ysc,
                                                   const int* __restrict__ rowptr,
                                                   const unsigned int* __restrict__ edges,
                                                   int n) {
    int lane = threadIdx.x & 7;
    int node = (blockIdx.x * blockDim.x + threadIdx.x) >> 3;
    if (node >= n) return;
    int e0 = rowptr[node], e1 = rowptr[node + 1];
    float a0 = 0.f, a1 = 0.f, a2 = 0.f, a3 = 0.f, wacc = 0.f;
    int e = e0;
    int e8 = e0 + ((e1 - e0) & ~7);
    for (; e < e8; e += 8) {
        unsigned int r[8];
        #pragma unroll
        for (int u = 0; u < 8; ++u) r[u] = edges[e + u];
        unsigned int v[8];
        float s[8];
        #pragma unroll
        for (int u = 0; u < 8; ++u) {
            int srcn = (int)(r[u] & 0xffffu);
            v[u] = xin[(size_t)srcn * 8 + lane];   // 4B: 4 biased-uint8 feats
            s[u] = xsc[srcn];                      // broadcast across 8 lanes
        }
        #pragma unroll
        for (int u = 0; u < 8; ++u) {
            float w = bf2f((unsigned short)(r[u] >> 16)) * s[u];
            wacc += w;
            a0 += (float)(v[u] & 0xffu) * w;           // v_cvt_f32_ubyte0
            a1 += (float)((v[u] >> 8) & 0xffu) * w;
            a2 += (float)((v[u] >> 16) & 0xffu) * w;
            a3 += (float)(v[u] >> 24) * w;
        }
    }
    for (; e < e1; ++e) {
        unsigned int r = edges[e];
        int srcn = (int)(r & 0xffffu);
        unsigned int v = xin[(size_t)srcn * 8 + lane];
        float w = bf2f((unsigned short)(r >> 16)) * xsc[srcn];
        wacc += w;
        a0 += (float)(v & 0xffu) * w;
        a1 += (float)((v >> 8) & 0xffu) * w;
        a2 += (float)((v >> 16) & 0xffu) * w;
        a3 += (float)(v >> 24) * w;
    }
    // fold out the +127 bias
    a0 -= 127.f * wacc; a1 -= 127.f * wacc; a2 -= 127.f * wacc; a3 -= 127.f * wacc;
    // per-node amax across the 8 lanes (32 feats) -> requantize
    float m = fmaxf(fmaxf(fabsf(a0), fabsf(a1)), fmaxf(fabsf(a2), fabsf(a3)));
    m = fmaxf(m, __shfl_xor(m, 1, 8));
    m = fmaxf(m, __shfl_xor(m, 2, 8));
    m = fmaxf(m, __shfl_xor(m, 4, 8));
    float inv = (m > 1e-30f) ? 127.f / m : 0.f;
    int q0 = __float2int_rn(a0 * inv) + 127;
    int q1 = __float2int_rn(a1 * inv) + 127;
    int q2 = __float2int_rn(a2 * inv) + 127;
    int q3 = __float2int_rn(a3 * inv) + 127;
    yout[(size_t)node * 8 + lane] = pack8(q0, q1, q2, q3);
    if (lane == 0) ysc[node] = (m > 1e-30f) ? m * (1.f / 127.f) : 0.f;
}

// ---------------- fused pooling: 10 terms, 64 graphs x 16 slices -------------
// Mean fused in. term k covers out cols [32k,32k+32); Q==nullptr -> raw P else
// |P-Q|, dequantizing int8+scale on the fly (scale loads are broadcasts).

struct PoolArgs10 {
    const unsigned char* P[10];
    const unsigned char* Q[10];
    const float* PS[10];
    const float* QS[10];
};

__global__ __launch_bounds__(320) void pool_kernel(PoolArgs10 a, const int* __restrict__ gstart,
                                                   float* __restrict__ out) {
    int k = threadIdx.x >> 5;
    int f = threadIdx.x & 31;
    int g = blockIdx.x >> 4;
    int s = blockIdx.x & 15;
    int gs = gstart[g], ge = gstart[g + 1];
    int len = ge - gs;
    int i0 = gs + ((len * s) >> 4);
    int i1 = gs + ((len * (s + 1)) >> 4);
    const unsigned char* __restrict__ P = a.P[k];
    const unsigned char* __restrict__ Q = a.Q[k];
    const float* __restrict__ PS = a.PS[k];
    const float* __restrict__ QS = a.QS[k];
    float acc = 0.f;
    if (Q) {
        for (int i = i0; i < i1; ++i) {
            float p = ((float)P[(size_t)i * 32 + f] - 127.f) * PS[i];
            float q = ((float)Q[(size_t)i * 32 + f] - 127.f) * QS[i];
            acc += fabsf(p - q);
        }
    } else {
        for (int i = i0; i < i1; ++i)
            acc += ((float)P[(size_t)i * 32 + f] - 127.f) * PS[i];
    }
    if (i1 > i0) {
        float invl = 1.0f / (float)max(len, 1);
        atomicAdd(&out[g * FEATS + k * 32 + f], acc * invl);
    }
}

// ---------------- host launch ----------------

extern "C" void kernel_launch(void* const* d_in, const int* in_sizes, int n_in,
                              void* d_out, int out_size, void* d_ws, size_t ws_size,
                              hipStream_t stream) {
    const float* X     = (const float*)d_in[0];
    const int*   ei    = (const int*)d_in[1];
    const float* ew    = (const float*)d_in[2];
    const int*   batch = (const int*)d_in[3];
    float* out = (float*)d_out;

    const int N = N_NODES, E = N_EDGES;
    const int* src = ei;
    const int* dst = ei + E;

    char* base = (char*)d_ws;
    size_t off = 0;
    auto alloc = [&](size_t bytes) -> void* {
        void* p = base + off;
        off += (bytes + 255) & ~(size_t)255;
        return p;
    };
    // int8 diffusion chain buffers y[k] = quant(P^k X), k=0..12 (+ fp32 scales)
    unsigned char* y[13];
    float* sc[13];
    for (int k = 0; k <= 12; ++k) {
        y[k]  = (unsigned char*)alloc((size_t)N * 32);
        sc[k] = (float*)alloc((size_t)N * 4);
    }

    int*  rowptr  = (int*)alloc((size_t)(N + 4) * 4);
    int*  gstart  = (int*)alloc((NUM_GRAPHS + 1) * 4);
    int*  counts  = (int*)alloc((size_t)NCHUNK * NBIN * 4);
    int*  binBase = (int*)alloc((NBIN + 1) * 4);
    int2* tmp     = (int2*)alloc((size_t)E * 8);
    unsigned int* edges = (unsigned int*)alloc((size_t)E * 4);

    hipMemsetAsync(out, 0, (size_t)out_size * 4, stream);

    // atomic-free CSR build: counts -> positions -> grouped tmp -> edges+rowptr
    binA_kernel<<<NCHUNK, 256, 0, stream>>>(dst, counts, E);
    binB_kernel<<<1, NBIN, 0, stream>>>(counts, binBase);
    binC_kernel<<<NCHUNK, 256, 0, stream>>>(src, dst, ew, counts, tmp, E);
    place_kernel<<<NPB, 256, 0, stream>>>(binBase, tmp, edges, rowptr, N);

    // X -> int8+scale + graph boundaries (merged)
    prep_kernel<<<(N * 8 + 255) / 256, 256, 0, stream>>>((const float4*)X, (unsigned int*)y[0],
                                                         sc[0], batch, gstart, N);

    // ---- single D=32 int8 diffusion chain: y[k] = quant(P y[k-1]), k = 1..12
    const int SPMM_GRID = (N * 8 + 255) / 256;  // 1563 blocks, 32 nodes/block
    for (int k = 1; k <= 12; ++k) {
        spmm_kernel<<<SPMM_GRID, 256, 0, stream>>>((const unsigned int*)y[k - 1], sc[k - 1],
                                                   (unsigned int*)y[k], sc[k],
                                                   rowptr, edges, N);
    }

    // ---- fused pooling (mean included) of all 10 feature column-blocks
    // F0 = y8 | F1: |y1-y2|, |y2-y4|, |y4-y8|
    // F2 (ref order): |y3-y2|, |y5-y3|, |y9-y5|, |y6-y4|, |y10-y6|, |y12-y8|
    {
        PoolArgs10 p{};
        const int Pi[10] = {8, 1, 2, 4, 3, 5, 9, 6, 10, 12};
        const int Qi[10] = {-1, 2, 4, 8, 2, 3, 5, 4, 6, 8};
        for (int k = 0; k < 10; ++k) {
            p.P[k]  = y[Pi[k]];
            p.PS[k] = sc[Pi[k]];
            p.Q[k]  = (Qi[k] < 0) ? nullptr : y[Qi[k]];
            p.QS[k] = (Qi[k] < 0) ? nullptr : sc[Qi[k]];
        }
        pool_kernel<<<NUM_GRAPHS * 16, 320, 0, stream>>>(p, gstart, out);
    }
}

// Round 2
// 267.874 us; speedup vs baseline: 1.1160x; 1.1160x over previous
//
#include <hip/hip_runtime.h>

#define N_NODES 50000
#define N_EDGES 800000
#define D_FEAT 32
#define NUM_GRAPHS 64
#define FEATS 320
#define NBIN 128                         // bins of 512 nodes (98 used)
#define BINSH 9
#define CE 4096                          // edges per binning chunk
#define NCHUNK ((N_EDGES + CE - 1) / CE) // 196
#define NPB ((N_NODES + 511) / 512)      // 98 place blocks

// bf16 helpers (RNE pack, shift unpack) — values finite, no NaN path needed
__device__ __forceinline__ unsigned short f2bf(float f) {
    unsigned int u = __float_as_uint(f);
    u = (u + 0x7fffu + ((u >> 16) & 1u)) >> 16;
    return (unsigned short)u;
}
__device__ __forceinline__ float bf2f(unsigned short h) {
    return __uint_as_float((unsigned int)h << 16);
}
// bf16 pair unpack straight from a packed dword (1 VALU op each)
__device__ __forceinline__ float bflo(unsigned int u) { return __uint_as_float(u << 16); }
__device__ __forceinline__ float bfhi(unsigned int u) { return __uint_as_float(u & 0xffff0000u); }

// ---------------- atomic-free binning sort (counts -> positions -> place) ----

__global__ void binA_kernel(const int* __restrict__ dst, int* __restrict__ counts, int n) {
    __shared__ int h[NBIN];
    int t = threadIdx.x;
    if (t < NBIN) h[t] = 0;
    __syncthreads();
    int s0 = blockIdx.x * CE, e0 = min(s0 + CE, n);
    for (int i = s0 + t; i < e0; i += blockDim.x)
        atomicAdd(&h[dst[i] >> BINSH], 1);
    __syncthreads();
    if (t < NBIN) counts[blockIdx.x * NBIN + t] = h[t];
}

__global__ void binB_kernel(int* __restrict__ counts, int* __restrict__ binBase) {
    __shared__ int s[NBIN];
    int b = threadIdx.x;
    int tot = 0;
    #pragma unroll 8
    for (int c = 0; c < NCHUNK; ++c) tot += counts[c * NBIN + b];
    s[b] = tot;
    __syncthreads();
    for (int off = 1; off < NBIN; off <<= 1) {
        int u = (b >= off) ? s[b - off] : 0;
        __syncthreads();
        s[b] += u;
        __syncthreads();
    }
    int base = s[b] - tot;   // exclusive
    binBase[b] = base;
    if (b == NBIN - 1) binBase[NBIN] = s[b];
    int running = base;
    #pragma unroll 4
    for (int c = 0; c < NCHUNK; ++c) {
        int idx = c * NBIN + b;
        int v = counts[idx];
        counts[idx] = running;
        running += v;
    }
}

__global__ __launch_bounds__(256) void binC_kernel(const int* __restrict__ src,
                                                   const int* __restrict__ dst,
                                                   const float* __restrict__ w,
                                                   const int* __restrict__ counts,
                                                   int2* __restrict__ tmp, int n) {
    __shared__ int h[NBIN], sc[NBIN], cur[NBIN], gbase[NBIN];
    __shared__ int2 srec[CE];
    __shared__ unsigned char sbin[CE];
    int t = threadIdx.x;
    if (t < NBIN) h[t] = 0;
    __syncthreads();
    int s0 = blockIdx.x * CE, e0 = min(s0 + CE, n);
    int cnt = e0 - s0;
    for (int i = s0 + t; i < e0; i += blockDim.x)
        atomicAdd(&h[dst[i] >> BINSH], 1);
    __syncthreads();
    if (t < NBIN) sc[t] = h[t];
    __syncthreads();
    for (int off = 1; off < NBIN; off <<= 1) {
        int u = (t < NBIN && t >= off) ? sc[t - off] : 0;
        __syncthreads();
        if (t < NBIN) sc[t] += u;   // inclusive; exclusive = sc[b]-h[b]
        __syncthreads();
    }
    if (t < NBIN) {
        cur[t] = 0;
        gbase[t] = counts[blockIdx.x * NBIN + t];
    }
    __syncthreads();
    for (int i = s0 + t; i < e0; i += blockDim.x) {
        int d = dst[i];
        int b = d >> BINSH;
        int pos = (sc[b] - h[b]) + atomicAdd(&cur[b], 1);   // LDS atomic: cheap
        srec[pos] = make_int2(src[i] | ((int)f2bf(w[i]) << 16), d & 511);
        sbin[pos] = (unsigned char)b;
    }
    __syncthreads();
    for (int j = t; j < cnt; j += blockDim.x) {
        int b = sbin[j];
        tmp[gbase[b] + (j - (sc[b] - h[b]))] = srec[j];   // coalesced runs per bin
    }
}

__global__ __launch_bounds__(256) void place_kernel(const int* __restrict__ binBase,
                                                    const int2* __restrict__ tmp,
                                                    unsigned int* __restrict__ edges,
                                                    int* __restrict__ rowptr, int n) {
    __shared__ int h[512], sc[512], cur[512];
    int b = blockIdx.x;
    int t = threadIdx.x;
    int base = binBase[b], end = binBase[b + 1];
    for (int i = t; i < 512; i += 256) { h[i] = 0; cur[i] = 0; }
    __syncthreads();
    for (int e = base + t; e < end; e += 256)
        atomicAdd(&h[tmp[e].y], 1);
    __syncthreads();
    for (int i = t; i < 512; i += 256) sc[i] = h[i];
    __syncthreads();
    for (int off = 1; off < 512; off <<= 1) {
        int i0 = t, i1 = t + 256;
        int a0 = (i0 >= off) ? sc[i0 - off] : 0;
        int a1 = (i1 >= off) ? sc[i1 - off] : 0;
        __syncthreads();
        sc[i0] += a0;
        sc[i1] += a1;
        __syncthreads();
    }
    int node0 = b << BINSH;
    for (int i = t; i < 512; i += 256) {
        int node = node0 + i;
        if (node <= n) rowptr[node] = base + sc[i] - h[i];   // exclusive
    }
    if (b == 0 && t == 0) rowptr[0] = 0;
    __syncthreads();
    for (int e = base + t; e < end; e += 256) {
        int2 p = tmp[e];
        int loc = p.y;
        int pos = base + (sc[loc] - h[loc]) + atomicAdd(&cur[loc], 1);
        edges[pos] = (unsigned int)p.x;
    }
}

// ---------------- prep: X -> bf16 conversion + graph boundaries -------------

__global__ void prep_kernel(const float4* __restrict__ xin, ushort4* __restrict__ xout,
                            const int* __restrict__ batch, int* __restrict__ gstart, int n) {
    int i = blockIdx.x * blockDim.x + threadIdx.x;
    if (i < n * 8) {
        float4 v = xin[i];
        ushort4 o;
        o.x = f2bf(v.x); o.y = f2bf(v.y); o.z = f2bf(v.z); o.w = f2bf(v.w);
        xout[i] = o;
    }
    if (i < n) {
        int g = batch[i];
        int gp = (i == 0) ? -1 : batch[i - 1];
        for (int gg = gp + 1; gg <= g; ++gg) gstart[gg] = i;
        if (i == n - 1)
            for (int gg = g + 1; gg <= NUM_GRAPHS; ++gg) gstart[gg] = n;
    }
}

// ---------------- SpMM (pull, no atomics), D=32 bf16, 4B edge recs ----------
// r1 finding: int8 (half the bytes, 2 req/edge) == bf16 (1 req/edge) in time
// => SpMM is TRANSACTION/latency-bound (~2 random req/cy/XCD observed), not
// byte-bound. So: bf16 state (1 req/edge, no scale stream) + maximize MLP:
// 4 lanes/node (lane owns 8 cols = one dwordx4 = the full 64B row coalesced),
// 16-deep unroll => 16 outstanding gathers per node-group, half the dependent
// vmcnt rounds per wave vs the old 8-lane/8-unroll shape. No epilogue shuffles.

__global__ __launch_bounds__(256, 4) void spmm_kernel(const uint4* __restrict__ xin,
                                                      uint4* __restrict__ yout,
                                                      const int* __restrict__ rowptr,
                                                      const unsigned int* __restrict__ edges,
                                                      int n) {
    int lane = threadIdx.x & 3;
    int node = (blockIdx.x * blockDim.x + threadIdx.x) >> 2;
    if (node >= n) return;
    int e0 = rowptr[node], e1 = rowptr[node + 1];
    float a0 = 0.f, a1 = 0.f, a2 = 0.f, a3 = 0.f;
    float a4 = 0.f, a5 = 0.f, a6 = 0.f, a7 = 0.f;
    int e = e0;
    int e16 = e0 + ((e1 - e0) & ~15);
    for (; e < e16; e += 16) {
        unsigned int r[16];
        #pragma unroll
        for (int u = 0; u < 16; ++u) r[u] = edges[e + u];
        uint4 v[16];
        #pragma unroll
        for (int u = 0; u < 16; ++u)
            v[u] = xin[(size_t)(r[u] & 0xffffu) * 4 + lane];
        #pragma unroll
        for (int u = 0; u < 16; ++u) {
            float w = bfhi(r[u]);
            a0 += bflo(v[u].x) * w; a1 += bfhi(v[u].x) * w;
            a2 += bflo(v[u].y) * w; a3 += bfhi(v[u].y) * w;
            a4 += bflo(v[u].z) * w; a5 += bfhi(v[u].z) * w;
            a6 += bflo(v[u].w) * w; a7 += bfhi(v[u].w) * w;
        }
    }
    int e4 = e0 + ((e1 - e0) & ~3);
    for (; e < e4; e += 4) {
        unsigned int r[4];
        #pragma unroll
        for (int u = 0; u < 4; ++u) r[u] = edges[e + u];
        uint4 v[4];
        #pragma unroll
        for (int u = 0; u < 4; ++u)
            v[u] = xin[(size_t)(r[u] & 0xffffu) * 4 + lane];
        #pragma unroll
        for (int u = 0; u < 4; ++u) {
            float w = bfhi(r[u]);
            a0 += bflo(v[u].x) * w; a1 += bfhi(v[u].x) * w;
            a2 += bflo(v[u].y) * w; a3 += bfhi(v[u].y) * w;
            a4 += bflo(v[u].z) * w; a5 += bfhi(v[u].z) * w;
            a6 += bflo(v[u].w) * w; a7 += bfhi(v[u].w) * w;
        }
    }
    for (; e < e1; ++e) {
        unsigned int r = edges[e];
        uint4 v = xin[(size_t)(r & 0xffffu) * 4 + lane];
        float w = bfhi(r);
        a0 += bflo(v.x) * w; a1 += bfhi(v.x) * w;
        a2 += bflo(v.y) * w; a3 += bfhi(v.y) * w;
        a4 += bflo(v.z) * w; a5 += bfhi(v.z) * w;
        a6 += bflo(v.w) * w; a7 += bfhi(v.w) * w;
    }
    uint4 o;
    o.x = (unsigned int)f2bf(a0) | ((unsigned int)f2bf(a1) << 16);
    o.y = (unsigned int)f2bf(a2) | ((unsigned int)f2bf(a3) << 16);
    o.z = (unsigned int)f2bf(a4) | ((unsigned int)f2bf(a5) << 16);
    o.w = (unsigned int)f2bf(a6) | ((unsigned int)f2bf(a7) << 16);
    yout[(size_t)node * 4 + lane] = o;
}

// ---------------- fused pooling: one pass, 10 distinct arrays loaded once ----
// Old pool read P,Q per term = 20 array-reads (64MB). All 10 terms derive from
// 10 distinct chain arrays {y1..y6,y8,y9,y10,y12}: load each node-row once
// (32MB total), compute all 10 terms, block-reduce in LDS, 320 atomics/block.

struct PoolPtrs { const unsigned short* a[10]; }; // y1,y2,y3,y4,y5,y6,y8,y9,y10,y12

__global__ __launch_bounds__(256) void pool_kernel(PoolPtrs P, const int* __restrict__ gstart,
                                                   float* __restrict__ out) {
    __shared__ float red[8][FEATS];
    int t = threadIdx.x;
    int f = t & 31;
    int sub = t >> 5;                 // 0..7
    int g = blockIdx.x >> 4;
    int s = blockIdx.x & 15;
    int gs = gstart[g], ge = gstart[g + 1];
    int len = ge - gs;
    int i0 = gs + ((len * s) >> 4);
    int i1 = gs + ((len * (s + 1)) >> 4);
    float acc[10];
    #pragma unroll
    for (int k = 0; k < 10; ++k) acc[k] = 0.f;
    for (int i = i0 + sub; i < i1; i += 8) {
        float v[10];
        #pragma unroll
        for (int k = 0; k < 10; ++k) v[k] = bf2f(P.a[k][(size_t)i * 32 + f]);
        acc[0] += v[6];                  // F0: y8
        acc[1] += fabsf(v[0] - v[1]);    // |y1-y2|
        acc[2] += fabsf(v[1] - v[3]);    // |y2-y4|
        acc[3] += fabsf(v[3] - v[6]);    // |y4-y8|
        acc[4] += fabsf(v[2] - v[1]);    // |y3-y2|
        acc[5] += fabsf(v[4] - v[2]);    // |y5-y3|
        acc[6] += fabsf(v[7] - v[4]);    // |y9-y5|
        acc[7] += fabsf(v[5] - v[3]);    // |y6-y4|
        acc[8] += fabsf(v[8] - v[5]);    // |y10-y6|
        acc[9] += fabsf(v[9] - v[6]);    // |y12-y8|
    }
    #pragma unroll
    for (int k = 0; k < 10; ++k) red[sub][k * 32 + f] = acc[k];
    __syncthreads();
    float invl = 1.0f / (float)max(len, 1);
    for (int o = t; o < FEATS; o += 256) {
        float ssum = 0.f;
        #pragma unroll
        for (int j = 0; j < 8; ++j) ssum += red[j][o];
        if (ssum != 0.f || true) atomicAdd(&out[g * FEATS + o], ssum * invl);
    }
}

// ---------------- host launch ----------------

extern "C" void kernel_launch(void* const* d_in, const int* in_sizes, int n_in,
                              void* d_out, int out_size, void* d_ws, size_t ws_size,
                              hipStream_t stream) {
    const float* X     = (const float*)d_in[0];
    const int*   ei    = (const int*)d_in[1];
    const float* ew    = (const float*)d_in[2];
    const int*   batch = (const int*)d_in[3];
    float* out = (float*)d_out;

    const int N = N_NODES, E = N_EDGES;
    const int* src = ei;
    const int* dst = ei + E;

    char* base = (char*)d_ws;
    size_t off = 0;
    auto alloc = [&](size_t bytes) -> void* {
        void* p = base + off;
        off += (bytes + 255) & ~(size_t)255;
        return p;
    };
    // bf16 diffusion chain buffers y[k] = P^k X, k=0..12 (y[0] = bf16(X))
    unsigned short* y[13];
    for (int k = 0; k <= 12; ++k) y[k] = (unsigned short*)alloc((size_t)N * 32 * 2);

    int*  rowptr  = (int*)alloc((size_t)(N + 4) * 4);
    int*  gstart  = (int*)alloc((NUM_GRAPHS + 1) * 4);
    int*  counts  = (int*)alloc((size_t)NCHUNK * NBIN * 4);
    int*  binBase = (int*)alloc((NBIN + 1) * 4);
    int2* tmp     = (int2*)alloc((size_t)E * 8);
    unsigned int* edges = (unsigned int*)alloc((size_t)E * 4);

    hipMemsetAsync(out, 0, (size_t)out_size * 4, stream);

    // atomic-free CSR build: counts -> positions -> grouped tmp -> edges+rowptr
    binA_kernel<<<NCHUNK, 256, 0, stream>>>(dst, counts, E);
    binB_kernel<<<1, NBIN, 0, stream>>>(counts, binBase);
    binC_kernel<<<NCHUNK, 256, 0, stream>>>(src, dst, ew, counts, tmp, E);
    place_kernel<<<NPB, 256, 0, stream>>>(binBase, tmp, edges, rowptr, N);

    // X -> bf16 + graph boundaries (merged)
    prep_kernel<<<(N * 8 + 255) / 256, 256, 0, stream>>>((const float4*)X, (ushort4*)y[0],
                                                         batch, gstart, N);

    // ---- single D=32 bf16 diffusion chain: y[k] = P y[k-1], k = 1..12
    const int SPMM_GRID = (N * 4 + 255) / 256;  // 782 blocks, 64 nodes/block
    for (int k = 1; k <= 12; ++k) {
        spmm_kernel<<<SPMM_GRID, 256, 0, stream>>>((const uint4*)y[k - 1], (uint4*)y[k],
                                                   rowptr, edges, N);
    }

    // ---- fused single-pass pooling (mean included) of all 10 terms
    // F0 = y8 | F1: |y1-y2|, |y2-y4|, |y4-y8|
    // F2 (ref order): |y3-y2|, |y5-y3|, |y9-y5|, |y6-y4|, |y10-y6|, |y12-y8|
    {
        PoolPtrs p;
        const int idx[10] = {1, 2, 3, 4, 5, 6, 8, 9, 10, 12};
        for (int k = 0; k < 10; ++k) p.a[k] = y[idx[k]];
        pool_kernel<<<NUM_GRAPHS * 16, 256, 0, stream>>>(p, gstart, out);
    }
}